// Round 3
// baseline (121.643 us; speedup 1.0000x reference)
//
#include <hip/hip_runtime.h>
#include <math.h>

// B=8, CIN=64, COUT=64, N=16, H=W=32
// G[c](xy,hw) = gelu(zxy[c,xy] + zhw[c,hw]) is a function of a SUM ->
// Chebyshev interpolation in vv=zhw with R=8 nodes per c (err ~1e-5):
//   gelu(u+vv) ~= sum_r gelu(u + t_cr) * L_cr(vv)
// zhw range analytic: ch,cw in +/-[1/32,31/32] -> symmetric, hwid=(|w1c2|+|w1c3|)*31/32.
// SINGLE fused kernel (R3): dispatch count is a first-order cost (harness
// ws-poison fill ~42us + ~dozen reset memsets dominate the timed window).
//   phase 1 (wgemm): per-block Gs tile = gelu(zxy + t_cr) in LDS;
//       Wpart[ks,bi,cr] = sum_{xy chunk} v*Gs; VsumPart = row sums;
//       + 200-elem/origblock slice of the global tables (Ltab, Qm, Rb2).
//   device-scope grid barrier (manual, module-global gen counter; all 256
//       blocks co-resident: 68KB LDS -> 2 blocks/CU capacity, grid == #CU).
//   phase 2 (final): Wsum = sum_ks Wpart; M1 = Qm@Wsum; E = conv_b+bias+Rb2@Vsum;
//       out = M1@Ltab + conv_w@v + E (single 128-deep K loop).
// R1: final 512 thr (2 waves/SIMD), Wsum de-aliased, K-split GEMM. (-4.8us)
// R2: Qm reg-prefetch REGRESSED (+2.1us, VGPR pressure) -> reverted.
// R3: fuse wgemm+final via grid barrier; phase bodies identical to R1.
//
// ws layout (byte offsets):
#define WSB_LTAB  0u         // 64*1024 f32  Ltab[cr*1024+hw]
#define WSB_QM    262144u    // 8*64*64 f32  Qm[c*4096+o*64+i] (= sum_n params*w2 /1024)
#define WSB_RB2   393216u    // 64*64 f32    (= sum_n params*b2 /1024)
#define WSB_WPART 409600u    // 16*512*64 f32 Wpart[ks*32768 + (b*64+i)*64 + cr]
#define WSB_VSUMP 2506752u   // 16*512 f32   VsumPart[ks*512 + bi]
// total ~2.5 MB (ws is 256 MiB)

#define COS8_INIT {0.98078528f, 0.83146961f, 0.55557023f, 0.19509032f, \
                  -0.19509032f, -0.55557023f, -0.83146961f, -0.98078528f}

__device__ inline float gelu_exact(float z) {
    return 0.5f * z * (1.0f + erff(z * 0.70710678118f));
}

__device__ inline float cheb_hwid(const float* w1, int c) {
    return fmaxf((fabsf(w1[c * 4 + 2]) + fabsf(w1[c * 4 + 3])) * (31.0f / 32.0f), 1e-2f);
}

// Manual grid barrier. Module globals (NOT in poisoned ws); generation-based,
// self-resetting across graph replays. Agent-scope atomics + __threadfence for
// cross-XCD visibility (per-XCD L2s are not coherent).
__device__ unsigned int g_count = 0;
__device__ unsigned int g_gen = 0;

__device__ inline void grid_sync_n(unsigned int nblocks) {
    __syncthreads();                     // all block's stores issued & drained
    if (threadIdx.x == 0) {
        __threadfence();                 // flush this XCD's L2 (release)
        unsigned int gen = __hip_atomic_load(&g_gen, __ATOMIC_ACQUIRE,
                                             __HIP_MEMORY_SCOPE_AGENT);
        unsigned int arrived = __hip_atomic_fetch_add(&g_count, 1u, __ATOMIC_ACQ_REL,
                                                      __HIP_MEMORY_SCOPE_AGENT) + 1u;
        if (arrived == nblocks) {
            __hip_atomic_store(&g_count, 0u, __ATOMIC_RELAXED,
                               __HIP_MEMORY_SCOPE_AGENT);
            __hip_atomic_fetch_add(&g_gen, 1u, __ATOMIC_RELEASE,
                                   __HIP_MEMORY_SCOPE_AGENT);
        } else {
            while (__hip_atomic_load(&g_gen, __ATOMIC_ACQUIRE,
                                     __HIP_MEMORY_SCOPE_AGENT) == gen)
                __builtin_amdgcn_s_sleep(2);
        }
        __threadfence();                 // invalidate stale caches (acquire)
    }
    __syncthreads();
}

// grid 256 blocks x 512 thr (1 block/CU, 8 waves/CU both phases).
// LDS (67,968 B, overlaid across the barrier):
//   phase 1: half h in [0,2): Vs[16][68] + Gs[64][64] at float-off h*5184
//   phase 2: Ct[128*36] | Ys[128*64] | Ws[64*64] | Esh[32] | Vsh[64]
__global__ __launch_bounds__(512, 2) void fused_kernel(
        const float* __restrict__ v,      const float* __restrict__ params,
        const float* __restrict__ w1,     const float* __restrict__ b1,
        const float* __restrict__ w2,     const float* __restrict__ b2,
        const float* __restrict__ conv_w, const float* __restrict__ conv_b,
        const float* __restrict__ bias,   float* __restrict__ out,
        char* __restrict__ wsb) {
    const float COS8[8] = COS8_INIT;
    float* Ltab  = (float*)(wsb + WSB_LTAB);
    float* Qm    = (float*)(wsb + WSB_QM);
    float* Rb2   = (float*)(wsb + WSB_RB2);
    float* Wpart = (float*)(wsb + WSB_WPART);
    float* VsumP = (float*)(wsb + WSB_VSUMP);
    __shared__ float smem[16992];
    int t = threadIdx.x;

    // ===================== PHASE 1: wgemm (2 orig blocks / block) ==========
    {
        int h = t >> 8, tl = t & 255;
        int orig = blockIdx.x * 2 + h;       // 0..511 original wgemm block id
        int bx = orig & 31, by = orig >> 5;  // bi-tile, xy-chunk
        float* Vs = smem + h * 5184;         // [16][68]
        float* Gs = smem + h * 5184 + 1088;  // [64][64]
        int bi0 = bx * 16, xy0 = by * 64;
        {   // stage 16 v rows x 64 xy
            int r = tl >> 4, c4 = tl & 15;
            *(float4*)&Vs[r * 68 + c4 * 4] =
                *(const float4*)(v + (bi0 + r) * 1024 + xy0 + c4 * 4);
        }
        // Gs[xyl][cr] = gelu(zxy[c, xy0+xyl] + node_cr), 16 gelu/thread
        #pragma unroll
        for (int l = 0; l < 16; l++) {
            int e = tl + l * 256;            // 4096 = 64 xyl x 64 cr
            int xyl = e >> 6, cr = e & 63, c = cr >> 3, r = cr & 7;
            int xy = xy0 + xyl;
            float cx = 2.0f * (((xy >> 5) + 0.5f) / 32.0f) - 1.0f;
            float cy = 2.0f * (((xy & 31) + 0.5f) / 32.0f) - 1.0f;
            float z = cx * w1[c * 4 + 0] + cy * w1[c * 4 + 1] + b1[c]
                    + cheb_hwid(w1, c) * COS8[r];
            Gs[xyl * 64 + cr] = gelu_exact(z);
        }
        __syncthreads();
        int bl = tl >> 4, crq = tl & 15;
        float4 acc = make_float4(0.f, 0.f, 0.f, 0.f);
        float vs = 0.0f;
        #pragma unroll 8
        for (int xy = 0; xy < 64; xy++) {
            float a = Vs[bl * 68 + xy];
            float4 g = *(const float4*)&Gs[xy * 64 + crq * 4];
            acc.x += a * g.x; acc.y += a * g.y; acc.z += a * g.z; acc.w += a * g.w;
            vs += a;
        }
        *(float4*)(Wpart + (size_t)by * 32768 + (bi0 + bl) * 64 + crq * 4) = acc;
        if (crq == 0) VsumP[by * 512 + bi0 + bl] = vs;

        // table slice: 512 origblocks x 200 elems covers 65536+32768+4096=102400
        int u = (by * 32 + bx) * 200 + tl;
        if (tl < 200) {
            if (u < 65536) {                 // Ltab[cr*1024 + hw]
                int cr = u >> 10, hw = u & 1023, c = cr >> 3, r = cr & 7;
                float hwid = cheb_hwid(w1, c);
                float ch = 2.0f * (((hw >> 5) + 0.5f) / 32.0f) - 1.0f;
                float cw = 2.0f * (((hw & 31) + 0.5f) / 32.0f) - 1.0f;
                float vv = ch * w1[c * 4 + 2] + cw * w1[c * 4 + 3];
                float tr = hwid * COS8[r];
                float p = 1.0f, d = 1.0f;
                #pragma unroll
                for (int s = 0; s < 8; s++)
                    if (s != r) {
                        float ts = hwid * COS8[s];
                        p *= (vv - ts);
                        d *= (tr - ts);
                    }
                Ltab[u] = p / d;
            } else if (u < 98304) {          // Qm[c*4096 + o*64 + i]
                int u2 = u - 65536;
                int c = u2 >> 12, oi = u2 & 4095;
                float s = 0.0f;
                #pragma unroll
                for (int n = 0; n < 16; n++)
                    s += params[n * 4096 + oi] * w2[n * 8 + c];
                Qm[u2] = s * (1.0f / 1024.0f);
            } else {                         // Rb2[o*64 + i]
                int oi = u - 98304;
                float s = 0.0f;
                #pragma unroll
                for (int n = 0; n < 16; n++)
                    s += params[n * 4096 + oi] * b2[n];
                Rb2[oi] = s * (1.0f / 1024.0f);
            }
        }
    }

    // ===================== GRID BARRIER ====================================
    grid_sync_n(256u);

    // ===================== PHASE 2: final (verbatim R1 body) ===============
    {
        float* Ct  = smem;                  // [128][36]
        float* Ys  = smem + 4608;           // [128][64]
        float* Ws  = smem + 12800;          // [64][64]
        float* Esh = smem + 16896;          // [32]
        float* Vsh = smem + 16928;          // [64]
        int bf = blockIdx.x;
        int hw0 = (bf & 15) * 64, o0 = ((bf >> 4) & 1) * 32, b = bf >> 5;

        // --- phase B: Wsum reduction (critical path: feeds M1) ---
        {
            int e0 = t * 8;                 // 4096 Wsum elems, 8 per thread
            float4 a0 = make_float4(0.f, 0.f, 0.f, 0.f);
            float4 a1 = make_float4(0.f, 0.f, 0.f, 0.f);
            const float* wp = Wpart + b * 4096 + e0;
            #pragma unroll
            for (int ks = 0; ks < 16; ks++) {
                const float4* p = (const float4*)(wp + (size_t)ks * 32768);
                float4 x0 = p[0], x1 = p[1];
                a0.x += x0.x; a0.y += x0.y; a0.z += x0.z; a0.w += x0.w;
                a1.x += x1.x; a1.y += x1.y; a1.z += x1.z; a1.w += x1.w;
            }
            *(float4*)&Ws[e0]     = a0;
            *(float4*)&Ws[e0 + 4] = a1;
        }
        if (t < 64) {
            float s = 0.0f;
            #pragma unroll
            for (int ks = 0; ks < 16; ks++) s += VsumP[ks * 512 + b * 64 + t];
            Vsh[t] = s;
        }
        // --- phase A: staging for the output GEMM (overlaps phase B) ---
        #pragma unroll
        for (int l = 0; l < 4; l++) {       // Ct rows 64..127 <- conv_w
            int e = t + l * 512;            // 2048 = 64 kk x 32 ol
            int kk = e >> 5, oc = e & 31;
            Ct[(64 + kk) * 36 + oc] = conv_w[(o0 + oc) * 64 + kk];
        }
        #pragma unroll
        for (int l = 0; l < 2; l++) {       // Ys rows 64..127 <- v
            int f = t + l * 512;            // 1024 float4s = 64 rows x 64 hw
            int k = f >> 4, q = f & 15;
            *(float4*)&Ys[(64 + k) * 64 + q * 4] =
                *(const float4*)(v + (size_t)b * 65536 + k * 1024 + hw0 + q * 4);
        }
        #pragma unroll
        for (int l = 0; l < 2; l++) {       // Ys rows 0..63 <- Ltab
            int f = t + l * 512;
            int k = f >> 4, q = f & 15;
            *(float4*)&Ys[k * 64 + q * 4] =
                *(const float4*)(Ltab + (size_t)k * 1024 + hw0 + q * 4);
        }
        __syncthreads();

        // --- phase C: M1 -> Ct rows 0..63; E -> Esh ---
        {
            int ol = t >> 4, c = (t >> 1) & 7, hi = t & 1;  // 32 x 8 x 2 = 512
            float a[4] = {};
            const float* qrow = Qm + c * 4096 + (o0 + ol) * 64;
            for (int i = 0; i < 64; i++) {
                float q = qrow[i];
                float4 w = *(const float4*)&Ws[i * 64 + c * 8 + hi * 4];
                a[0] += q * w.x; a[1] += q * w.y; a[2] += q * w.z; a[3] += q * w.w;
            }
            #pragma unroll
            for (int j = 0; j < 4; j++)
                Ct[(c * 8 + hi * 4 + j) * 36 + ol] = a[j];
        }
        if (t < 32) {
            int o = o0 + t;
            float s = conv_b[o] + bias[o];
            const float* rr = Rb2 + o * 64;
            for (int i = 0; i < 64; i++) s += rr[i] * Vsh[i];
            Esh[t] = s;
        }
        __syncthreads();

        // --- phase D: out = Ct^T @ Ys + E, K=128 split across thread halves ---
        int g = t >> 8, tt = t & 255;
        int ty = tt >> 5, tx = tt & 31;     // o = o0+ty*4+m, hw = hw0+tx*2+{0,1}
        float acc[4][2];
        #pragma unroll
        for (int m = 0; m < 4; m++) {
            float e = (g == 0) ? Esh[ty * 4 + m] : 0.0f;
            acc[m][0] = e; acc[m][1] = e;
        }
        #pragma unroll 4
        for (int k = 0; k < 64; k++) {
            int kk = g * 64 + k;
            float4 cq = *(const float4*)&Ct[kk * 36 + ty * 4];
            float2 y = *(const float2*)&Ys[kk * 64 + tx * 2];
            acc[0][0] += cq.x * y.x; acc[0][1] += cq.x * y.y;
            acc[1][0] += cq.y * y.x; acc[1][1] += cq.y * y.y;
            acc[2][0] += cq.z * y.x; acc[2][1] += cq.z * y.y;
            acc[3][0] += cq.w * y.x; acc[3][1] += cq.w * y.y;
        }
        if (g == 1) {                       // Ws dead after phase C: combine scratch
            *(float4*)&Ws[tt * 8]     = make_float4(acc[0][0], acc[0][1], acc[1][0], acc[1][1]);
            *(float4*)&Ws[tt * 8 + 4] = make_float4(acc[2][0], acc[2][1], acc[3][0], acc[3][1]);
        }
        __syncthreads();
        if (g == 0) {
            float4 p0 = *(const float4*)&Ws[tt * 8];
            float4 p1 = *(const float4*)&Ws[tt * 8 + 4];
            acc[0][0] += p0.x; acc[0][1] += p0.y; acc[1][0] += p0.z; acc[1][1] += p0.w;
            acc[2][0] += p1.x; acc[2][1] += p1.y; acc[3][0] += p1.z; acc[3][1] += p1.w;
            #pragma unroll
            for (int m = 0; m < 4; m++) {
                *(float2*)(out + (size_t)b * 65536 + (o0 + ty * 4 + m) * 1024 + hw0 + tx * 2)
                    = make_float2(acc[m][0], acc[m][1]);
            }
        }
    }
}

extern "C" void kernel_launch(void* const* d_in, const int* in_sizes, int n_in,
                              void* d_out, int out_size, void* d_ws, size_t ws_size,
                              hipStream_t stream) {
    const float* v      = (const float*)d_in[0];
    const float* params = (const float*)d_in[1];
    const float* w1     = (const float*)d_in[2];
    const float* b1     = (const float*)d_in[3];
    const float* w2     = (const float*)d_in[4];
    const float* b2     = (const float*)d_in[5];
    const float* conv_w = (const float*)d_in[6];
    const float* conv_b = (const float*)d_in[7];
    const float* bias   = (const float*)d_in[8];
    float* out = (float*)d_out;
    char* wsb  = (char*)d_ws;

    fused_kernel<<<dim3(256), 512, 0, stream>>>(v, params, w1, b1, w2, b2,
                                                conv_w, conv_b, bias, out, wsb);
}

// Round 4
// 88.397 us; speedup vs baseline: 1.3761x; 1.3761x over previous
//
#include <hip/hip_runtime.h>
#include <hip/hip_bf16.h>
#include <math.h>

// B=8, CIN=64, COUT=64, N=16, H=W=32
// G[c](xy,hw) = gelu(zxy[c,xy] + zhw[c,hw]) is a function of a SUM ->
// Chebyshev interpolation in vv=zhw with R=8 nodes per c (err ~1e-5):
//   gelu(u+vv) ~= sum_r gelu(u + t_cr) * L_cr(vv)
// zhw range analytic: ch,cw in +/-[1/32,31/32] -> symmetric, hwid=(|w1c2|+|w1c3|)*31/32.
// TWO kernels (dispatch count is a first-order cost; harness ws-poison fill
// ~42us dominates the timed window and is not controllable):
//   wgemm: per-block Gs tile = gelu(zxy + t_cr) generated in LDS (no global Gtab);
//          Wpart[ks,bi,cr] = sum_{xy chunk} v*Gs; VsumPart[ks,bi] = row sums;
//          plus a 200-elem slice/block of the global tables (Ltab, Qm, Rb2).
//   final: Wsum = sum_ks Wpart; M1 = Qm@Wsum; E = conv_b+bias+Rb2@(sum_ks VsumPart);
//          out = M1@Ltab + conv_w@v + E    (single 128-deep K loop)
// R1: final 512 thr (2 waves/SIMD), Wsum de-aliased, K-split GEMM. (-4.8us) <- BEST
// R2: Qm reg-prefetch REGRESSED (+2.1us, VGPR pressure) -> reverted.
// R3: grid-barrier fusion REGRESSED (+33us: fused kernel 53us; agent-scope
//   acquire spin invalidates caches across 8 XCDs + threadfence L2 wbinv;
//   barrier >> the dispatch boundary it saved) -> reverted to R1.
//
// ws layout (byte offsets):
#define WSB_LTAB  0u         // 64*1024 f32  Ltab[cr*1024+hw]
#define WSB_QM    262144u    // 8*64*64 f32  Qm[c*4096+o*64+i] (= sum_n params*w2 /1024)
#define WSB_RB2   393216u    // 64*64 f32    (= sum_n params*b2 /1024)
#define WSB_WPART 409600u    // 16*512*64 f32 Wpart[ks*32768 + (b*64+i)*64 + cr]
#define WSB_VSUMP 2506752u   // 16*512 f32   VsumPart[ks*512 + bi]
// total ~2.5 MB (ws is 256 MiB)

#define COS8_INIT {0.98078528f, 0.83146961f, 0.55557023f, 0.19509032f, \
                  -0.19509032f, -0.55557023f, -0.83146961f, -0.98078528f}

__device__ inline float gelu_exact(float z) {
    return 0.5f * z * (1.0f + erff(z * 0.70710678118f));
}

__device__ inline float cheb_hwid(const float* w1, int c) {
    return fmaxf((fabsf(w1[c * 4 + 2]) + fabsf(w1[c * 4 + 3])) * (31.0f / 32.0f), 1e-2f);
}

// grid (32 bi-tiles, 16 xy-chunks), block 256; v read exactly once.
__global__ __launch_bounds__(256) void wgemm_kernel(const float* __restrict__ v,
                                                    const float* __restrict__ params,
                                                    const float* __restrict__ w1,
                                                    const float* __restrict__ b1,
                                                    const float* __restrict__ w2,
                                                    const float* __restrict__ b2,
                                                    char* __restrict__ wsb) {
    const float COS8[8] = COS8_INIT;
    float* Ltab  = (float*)(wsb + WSB_LTAB);
    float* Qm    = (float*)(wsb + WSB_QM);
    float* Rb2   = (float*)(wsb + WSB_RB2);
    float* Wpart = (float*)(wsb + WSB_WPART);
    float* VsumP = (float*)(wsb + WSB_VSUMP);
    __shared__ float Vs[16][68];
    __shared__ float Gs[64][64];
    int t = threadIdx.x;
    int bi0 = blockIdx.x * 16, xy0 = blockIdx.y * 64;
    {   // stage 16 v rows x 64 xy
        int r = t >> 4, c4 = t & 15;
        *(float4*)&Vs[r][c4 * 4] = *(const float4*)(v + (bi0 + r) * 1024 + xy0 + c4 * 4);
    }
    // generate Gs[xyl][cr] = gelu(zxy[c, xy0+xyl] + node_cr) in LDS (16 gelu/thread)
    #pragma unroll
    for (int l = 0; l < 16; l++) {
        int e = t + l * 256;                // 4096 = 64 xyl x 64 cr
        int xyl = e >> 6, cr = e & 63, c = cr >> 3, r = cr & 7;
        int xy = xy0 + xyl;
        float cx = 2.0f * (((xy >> 5) + 0.5f) / 32.0f) - 1.0f;
        float cy = 2.0f * (((xy & 31) + 0.5f) / 32.0f) - 1.0f;
        float z = cx * w1[c * 4 + 0] + cy * w1[c * 4 + 1] + b1[c]
                + cheb_hwid(w1, c) * COS8[r];
        Gs[xyl][cr] = gelu_exact(z);
    }
    __syncthreads();
    int bl = t >> 4, crq = t & 15;
    float4 acc = make_float4(0.f, 0.f, 0.f, 0.f);
    float vs = 0.0f;
    #pragma unroll 8
    for (int xy = 0; xy < 64; xy++) {
        float a = Vs[bl][xy];
        float4 g = *(const float4*)&Gs[xy][crq * 4];
        acc.x += a * g.x; acc.y += a * g.y; acc.z += a * g.z; acc.w += a * g.w;
        vs += a;
    }
    *(float4*)(Wpart + (size_t)blockIdx.y * 32768 + (bi0 + bl) * 64 + crq * 4) = acc;
    if (crq == 0) VsumP[blockIdx.y * 512 + bi0 + bl] = vs;

    // table slice: 512 blocks x 200 elems covers Ltab(65536)+Qm(32768)+Rb2(4096)=102400
    int bid = blockIdx.y * 32 + blockIdx.x;
    int u = bid * 200 + t;
    if (t < 200) {
        if (u < 65536) {                    // Ltab[cr*1024 + hw]
            int cr = u >> 10, hw = u & 1023, c = cr >> 3, r = cr & 7;
            float hwid = cheb_hwid(w1, c);
            float ch = 2.0f * (((hw >> 5) + 0.5f) / 32.0f) - 1.0f;
            float cw = 2.0f * (((hw & 31) + 0.5f) / 32.0f) - 1.0f;
            float vv = ch * w1[c * 4 + 2] + cw * w1[c * 4 + 3];
            float tr = hwid * COS8[r];
            float p = 1.0f, d = 1.0f;
            #pragma unroll
            for (int s = 0; s < 8; s++)
                if (s != r) {
                    float ts = hwid * COS8[s];
                    p *= (vv - ts);
                    d *= (tr - ts);
                }
            Ltab[u] = p / d;
        } else if (u < 98304) {             // Qm[c*4096 + o*64 + i]
            int u2 = u - 65536;
            int c = u2 >> 12, oi = u2 & 4095;
            float s = 0.0f;
            #pragma unroll
            for (int n = 0; n < 16; n++)
                s += params[n * 4096 + oi] * w2[n * 8 + c];
            Qm[u2] = s * (1.0f / 1024.0f);
        } else {                            // Rb2[o*64 + i]
            int oi = u - 98304;
            float s = 0.0f;
            #pragma unroll
            for (int n = 0; n < 16; n++)
                s += params[n * 4096 + oi] * b2[n];
            Rb2[oi] = s * (1.0f / 1024.0f);
        }
    }
}

// Fused M1 + E + output GEMM.
// grid (16 hw-tiles, 2 o-tiles, 8 b), block 512 (8 waves -> 2 waves/SIMD).
// LDS: Ct[128][36] (k<64: M1, k>=64: conv_w) + Ys[128][64] (k<64: Ltab, k>=64: v)
//      + Ws[64][64] Wsum (separate buffer: staging overlaps the reduction,
//        reused as the cross-half combine scratch in the output GEMM).
__global__ __launch_bounds__(512) void final_kernel(const float* __restrict__ v,
                                                    const float* __restrict__ conv_w,
                                                    const float* __restrict__ conv_b,
                                                    const float* __restrict__ bias,
                                                    float* __restrict__ out,
                                                    char* __restrict__ wsb) {
    const float* Ltab  = (const float*)(wsb + WSB_LTAB);
    const float* Qm    = (const float*)(wsb + WSB_QM);
    const float* Rb2   = (const float*)(wsb + WSB_RB2);
    const float* Wpart = (const float*)(wsb + WSB_WPART);
    const float* VsumP = (const float*)(wsb + WSB_VSUMP);
    __shared__ float Ct[128 * 36];      // 18 KB
    __shared__ float Ys[128 * 64];      // 32 KB
    __shared__ float Ws[64 * 64];       // 16 KB
    __shared__ float Esh[32];
    __shared__ float Vsh[64];
    int t = threadIdx.x;
    int hw0 = blockIdx.x * 64, o0 = blockIdx.y * 32, b = blockIdx.z;

    // --- phase B: Wsum reduction (critical path: feeds M1) — issue first ---
    {
        int e0 = t * 8;                 // 4096 Wsum elems, 8 per thread
        float4 a0 = make_float4(0.f, 0.f, 0.f, 0.f);
        float4 a1 = make_float4(0.f, 0.f, 0.f, 0.f);
        const float* wp = Wpart + b * 4096 + e0;
        #pragma unroll
        for (int ks = 0; ks < 16; ks++) {
            const float4* p = (const float4*)(wp + (size_t)ks * 32768);
            float4 x0 = p[0], x1 = p[1];
            a0.x += x0.x; a0.y += x0.y; a0.z += x0.z; a0.w += x0.w;
            a1.x += x1.x; a1.y += x1.y; a1.z += x1.z; a1.w += x1.w;
        }
        *(float4*)&Ws[e0]     = a0;
        *(float4*)&Ws[e0 + 4] = a1;
    }
    if (t < 64) {
        float s = 0.0f;
        #pragma unroll
        for (int ks = 0; ks < 16; ks++) s += VsumP[ks * 512 + b * 64 + t];
        Vsh[t] = s;
    }
    // --- phase A: staging (only needed by the output GEMM; overlaps phase B) ---
    #pragma unroll
    for (int l = 0; l < 4; l++) {       // Ct rows 64..127 <- conv_w
        int e = t + l * 512;            // 2048 = 64 kk x 32 ol
        int kk = e >> 5, ol = e & 31;
        Ct[(64 + kk) * 36 + ol] = conv_w[(o0 + ol) * 64 + kk];
    }
    #pragma unroll
    for (int l = 0; l < 2; l++) {       // Ys rows 64..127 <- v
        int f = t + l * 512;            // 1024 float4s = 64 rows x 64 hw
        int k = f >> 4, q = f & 15;
        *(float4*)&Ys[(64 + k) * 64 + q * 4] =
            *(const float4*)(v + (size_t)b * 65536 + k * 1024 + hw0 + q * 4);
    }
    #pragma unroll
    for (int l = 0; l < 2; l++) {       // Ys rows 0..63 <- Ltab (no alias now)
        int f = t + l * 512;
        int k = f >> 4, q = f & 15;
        *(float4*)&Ys[k * 64 + q * 4] =
            *(const float4*)(Ltab + (size_t)k * 1024 + hw0 + q * 4);
    }
    __syncthreads();

    // --- phase C: M1 -> Ct rows 0..63; E -> Esh ---
    {
        int ol = t >> 4, c = (t >> 1) & 7, hi = t & 1;  // 32 x 8 x 2 = 512
        float a[4] = {};
        const float* qrow = Qm + c * 4096 + (o0 + ol) * 64;
        for (int i = 0; i < 64; i++) {
            float q = qrow[i];
            float4 w = *(const float4*)&Ws[i * 64 + c * 8 + hi * 4];
            a[0] += q * w.x; a[1] += q * w.y; a[2] += q * w.z; a[3] += q * w.w;
        }
        #pragma unroll
        for (int j = 0; j < 4; j++)
            Ct[(c * 8 + hi * 4 + j) * 36 + ol] = a[j];
    }
    if (t < 32) {
        int o = o0 + t;
        float s = conv_b[o] + bias[o];
        const float* rr = Rb2 + o * 64;
        for (int i = 0; i < 64; i++) s += rr[i] * Vsh[i];
        Esh[t] = s;
    }
    __syncthreads();

    // --- phase D: out = Ct^T @ Ys + E, K=128 split across the two thread halves ---
    int g = t >> 8, tt = t & 255;
    int ty = tt >> 5, tx = tt & 31;     // o = o0+ty*4+m, hw = hw0+tx*2+{0,1}
    float acc[4][2];
    #pragma unroll
    for (int m = 0; m < 4; m++) {
        float e = (g == 0) ? Esh[ty * 4 + m] : 0.0f;
        acc[m][0] = e; acc[m][1] = e;
    }
    #pragma unroll 4
    for (int k = 0; k < 64; k++) {
        int kk = g * 64 + k;
        float4 cq = *(const float4*)&Ct[kk * 36 + ty * 4];
        float2 y = *(const float2*)&Ys[kk * 64 + tx * 2];
        acc[0][0] += cq.x * y.x; acc[0][1] += cq.x * y.y;
        acc[1][0] += cq.y * y.x; acc[1][1] += cq.y * y.y;
        acc[2][0] += cq.z * y.x; acc[2][1] += cq.z * y.y;
        acc[3][0] += cq.w * y.x; acc[3][1] += cq.w * y.y;
    }
    if (g == 1) {                       // Ws is dead after phase C: combine scratch
        *(float4*)&Ws[tt * 8]     = make_float4(acc[0][0], acc[0][1], acc[1][0], acc[1][1]);
        *(float4*)&Ws[tt * 8 + 4] = make_float4(acc[2][0], acc[2][1], acc[3][0], acc[3][1]);
    }
    __syncthreads();
    if (g == 0) {
        float4 p0 = *(const float4*)&Ws[tt * 8];
        float4 p1 = *(const float4*)&Ws[tt * 8 + 4];
        acc[0][0] += p0.x; acc[0][1] += p0.y; acc[1][0] += p0.z; acc[1][1] += p0.w;
        acc[2][0] += p1.x; acc[2][1] += p1.y; acc[3][0] += p1.z; acc[3][1] += p1.w;
        #pragma unroll
        for (int m = 0; m < 4; m++) {
            *(float2*)(out + (size_t)b * 65536 + (o0 + ty * 4 + m) * 1024 + hw0 + tx * 2)
                = make_float2(acc[m][0], acc[m][1]);
        }
    }
}

extern "C" void kernel_launch(void* const* d_in, const int* in_sizes, int n_in,
                              void* d_out, int out_size, void* d_ws, size_t ws_size,
                              hipStream_t stream) {
    const float* v      = (const float*)d_in[0];
    const float* params = (const float*)d_in[1];
    const float* w1     = (const float*)d_in[2];
    const float* b1     = (const float*)d_in[3];
    const float* w2     = (const float*)d_in[4];
    const float* b2     = (const float*)d_in[5];
    const float* conv_w = (const float*)d_in[6];
    const float* conv_b = (const float*)d_in[7];
    const float* bias   = (const float*)d_in[8];
    float* out = (float*)d_out;
    char* wsb  = (char*)d_ws;

    wgemm_kernel<<<dim3(32, 16), 256, 0, stream>>>(v, params, w1, b1, w2, b2, wsb);
    final_kernel<<<dim3(16, 2, 8), 512, 0, stream>>>(v, conv_w, conv_b, bias, out, wsb);
}